// Round 9
// baseline (5711.934 us; speedup 1.0000x reference)
//
#include <hip/hip_runtime.h>
#include <math.h>

// LSTM B=128,T=1024,D=64,H=256,C=6 — R9: R8 structure + AGPR weight residence.
//
// R8 counters: VGPR=256 (the VALU arch ceiling), FETCH ~xg-only, VALUBusy 14%,
// 5 us/step -> ~170 weight pairs/thread were spilling through L2 each step
// (invisible in FETCH since L2-resident), unhidden at 1 wave/SIMD.
// R9: overflow pairs pinned in AGPRs via "a"-constraint inline asm:
//   * groups 0..12  (pairs 0..51,  208 regs): named VGPR f16x2 (as R8)
//   * groups 13..23 (pairs 52..95, 176 regs): AGPR via volatile
//     v_accvgpr_write (prologue) / v_accvgpr_read (loop; volatile so the
//     reads can't be hoisted out of the loop and re-spilled)
//   * pairs 96..127: LDS [32][1024] f16x2 (128 KB, lane-consecutive b32)
// On-chip weight total = 208 V + 176 A + 128 LDS pairs = full K. Zero per-step
// L2 weight traffic. Everything else identical to R8 (passed, absmax 3.9e-3).

#define Tt 1024
#define Dd 64
#define Hh 256
#define G4 1024
#define Cc 6
#define BT (128 * 1024)
#define XG_BYTES ((size_t)BT * G4 * 2)   // 256 MB f16

typedef _Float16 f16x2 __attribute__((ext_vector_type(2)));

__device__ __forceinline__ float dot2(f16x2 a, f16x2 b, float c) {
#if __has_builtin(__builtin_amdgcn_fdot2)
    return __builtin_amdgcn_fdot2(a, b, c, false);
#else
    return c + (float)a.x * (float)b.x + (float)a.y * (float)b.y;
#endif
}
__device__ __forceinline__ float sigm(float p) { return 1.0f / (1.0f + __expf(-p)); }
__device__ __forceinline__ float tanh_fast(float p) {
    return 1.0f - 2.0f / (__expf(2.0f * p) + 1.0f);
}
__device__ __forceinline__ unsigned short f2h(float v) {
    _Float16 h = (_Float16)v;
    return __builtin_bit_cast(unsigned short, h);
}
__device__ __forceinline__ float h2f(unsigned short u) {
    return (float)__builtin_bit_cast(_Float16, u);
}
__device__ __forceinline__ f16x2 bcf(float v) { return __builtin_bit_cast(f16x2, v); }

// ---------------- stage 1: xg = x @ Wx + bias, f16 (verified R6-R8) --------
__global__ __launch_bounds__(256) void xg_gemm(
    const float* __restrict__ x, const float* __restrict__ Wx,
    const float* __restrict__ bias, unsigned short* __restrict__ xg)
{
    __shared__ float xs[32][65];
    __shared__ float wsl[64][256];

    const int tid = threadIdx.x;
    const long r0 = (long)blockIdx.x * 32;
    const int  c0 = blockIdx.y * 256;

    {
        const float4* src = (const float4*)(x + r0 * Dd);
        float4 v0 = src[tid], v1 = src[tid + 256];
        int e = tid * 4;
        xs[e >> 6][e & 63] = v0.x; xs[e >> 6][(e & 63) + 1] = v0.y;
        xs[e >> 6][(e & 63) + 2] = v0.z; xs[e >> 6][(e & 63) + 3] = v0.w;
        e += 1024;
        xs[e >> 6][e & 63] = v1.x; xs[e >> 6][(e & 63) + 1] = v1.y;
        xs[e >> 6][(e & 63) + 2] = v1.z; xs[e >> 6][(e & 63) + 3] = v1.w;
    }
    for (int i = tid; i < 64 * 64; i += 256) {
        int d = i >> 6, cq = i & 63;
        *(float4*)&wsl[d][cq * 4] = *(const float4*)(Wx + (long)d * G4 + c0 + cq * 4);
    }
    __syncthreads();

    const int r = tid & 31, cg = tid >> 5;
    float acc[32];
    #pragma unroll
    for (int c = 0; c < 32; ++c) acc[c] = bias[c0 + cg * 32 + c];
    for (int k = 0; k < 64; ++k) {
        float xv = xs[r][k];
        #pragma unroll
        for (int c = 0; c < 32; ++c) acc[c] += xv * wsl[k][cg * 32 + c];
    }
    unsigned int ow[16];
    #pragma unroll
    for (int c2 = 0; c2 < 16; ++c2)
        ow[c2] = (unsigned int)f2h(acc[2 * c2]) | ((unsigned int)f2h(acc[2 * c2 + 1]) << 16);
    uint4* dst = (uint4*)(xg + (r0 + r) * G4 + c0 + cg * 32);
    dst[0] = make_uint4(ow[0], ow[1], ow[2], ow[3]);
    dst[1] = make_uint4(ow[4], ow[5], ow[6], ow[7]);
    dst[2] = make_uint4(ow[8], ow[9], ow[10], ow[11]);
    dst[3] = make_uint4(ow[12], ow[13], ow[14], ow[15]);
}

// ---------------- stage 2: recurrence -------------------------------------
// pair index i covers k = 2i,2i+1; cols A,B,C,D = gates i,f,g,o of unit tid.

// V-resident pairs (groups 0..12 -> i = 0..51)
#define WLOADV4(i) \
  const f16x2 wA_##i = f16x2{(_Float16)Wh[(2*(i))*G4 + colA], (_Float16)Wh[(2*(i)+1)*G4 + colA]}; \
  const f16x2 wB_##i = f16x2{(_Float16)Wh[(2*(i))*G4 + colB], (_Float16)Wh[(2*(i)+1)*G4 + colB]}; \
  const f16x2 wC_##i = f16x2{(_Float16)Wh[(2*(i))*G4 + colC], (_Float16)Wh[(2*(i)+1)*G4 + colC]}; \
  const f16x2 wD_##i = f16x2{(_Float16)Wh[(2*(i))*G4 + colD], (_Float16)Wh[(2*(i)+1)*G4 + colD]};

// A-resident pairs (groups 13..23 -> i = 52..95): volatile accvgpr write/read
#define AW1(dst, cix, i) { \
    f16x2 t_ = f16x2{(_Float16)Wh[(2*(i))*G4 + (cix)], (_Float16)Wh[(2*(i)+1)*G4 + (cix)]}; \
    asm volatile("v_accvgpr_write_b32 %0, %1" : "=a"(dst) : "v"(__builtin_bit_cast(float, t_))); }

#define WLOADA4(i) \
  float awA_##i, awB_##i, awC_##i, awD_##i; \
  AW1(awA_##i, colA, i) AW1(awB_##i, colB, i) \
  AW1(awC_##i, colC, i) AW1(awD_##i, colD, i)

#define REPV52(M) \
  M(0) M(1) M(2) M(3) M(4) M(5) M(6) M(7) \
  M(8) M(9) M(10) M(11) M(12) M(13) M(14) M(15) \
  M(16) M(17) M(18) M(19) M(20) M(21) M(22) M(23) \
  M(24) M(25) M(26) M(27) M(28) M(29) M(30) M(31) \
  M(32) M(33) M(34) M(35) M(36) M(37) M(38) M(39) \
  M(40) M(41) M(42) M(43) M(44) M(45) M(46) M(47) \
  M(48) M(49) M(50) M(51)

#define REPA44(M) \
  M(52) M(53) M(54) M(55) M(56) M(57) M(58) M(59) \
  M(60) M(61) M(62) M(63) M(64) M(65) M(66) M(67) \
  M(68) M(69) M(70) M(71) M(72) M(73) M(74) M(75) \
  M(76) M(77) M(78) M(79) M(80) M(81) M(82) M(83) \
  M(84) M(85) M(86) M(87) M(88) M(89) M(90) M(91) \
  M(92) M(93) M(94) M(95)

#define DOTPV(i, hh) { f16x2 h_ = (hh); \
    aA = dot2(h_, wA_##i, aA); aB = dot2(h_, wB_##i, aB); \
    aC = dot2(h_, wC_##i, aC); aD = dot2(h_, wD_##i, aD); }

#define DOTPA(i, hh) { f16x2 h_ = (hh); float tA_, tB_, tC_, tD_; \
    asm volatile("v_accvgpr_read_b32 %0, %1" : "=v"(tA_) : "a"(awA_##i)); \
    asm volatile("v_accvgpr_read_b32 %0, %1" : "=v"(tB_) : "a"(awB_##i)); \
    asm volatile("v_accvgpr_read_b32 %0, %1" : "=v"(tC_) : "a"(awC_##i)); \
    asm volatile("v_accvgpr_read_b32 %0, %1" : "=v"(tD_) : "a"(awD_##i)); \
    aA = dot2(h_, bcf(tA_), aA); aB = dot2(h_, bcf(tB_), aB); \
    aC = dot2(h_, bcf(tC_), aC); aD = dot2(h_, bcf(tD_), aD); }

#define DOTG4V(g, i0,i1,i2,i3) { float4 hC_ = hvf4[g]; \
    DOTPV(i0, bcf(hC_.x)) DOTPV(i1, bcf(hC_.y)) \
    DOTPV(i2, bcf(hC_.z)) DOTPV(i3, bcf(hC_.w)) }

#define DOTG4A(g, i0,i1,i2,i3) { float4 hC_ = hvf4[g]; \
    DOTPA(i0, bcf(hC_.x)) DOTPA(i1, bcf(hC_.y)) \
    DOTPA(i2, bcf(hC_.z)) DOTPA(i3, bcf(hC_.w)) }

__global__ __launch_bounds__(256, 1) void lstm_xg(
    const unsigned short* __restrict__ xg,  // [B,T,1024] f16, bias folded
    const float* __restrict__ Wh,           // [H,4H]
    const float* __restrict__ Wout,         // [H,C]
    const float* __restrict__ bout,         // [C]
    float* __restrict__ out)                // [B,T,C]
{
    __shared__ alignas(16) unsigned short h_f16[Hh];  // current h
    __shared__ f16x2 wl[32][G4];                      // Wh pairs 96..127, 128 KB
    __shared__ float wout_t[Cc][Hh];
    __shared__ float bout_l[8];

    const int tid  = threadIdx.x;
    const int b    = blockIdx.x;
    const int colA = tid;          // gate i of unit tid
    const int colB = tid + 256;    // f
    const int colC = tid + 512;    // g
    const int colD = tid + 768;    // o

    // ---- prologue: 208 V-regs + 176 AGPRs + LDS tail ----
    REPV52(WLOADV4)
    REPA44(WLOADA4)

    #pragma unroll
    for (int j = 0; j < 32; ++j) {
        wl[j][colA] = f16x2{(_Float16)Wh[(192 + 2*j)*G4 + colA],
                            (_Float16)Wh[(193 + 2*j)*G4 + colA]};
        wl[j][colB] = f16x2{(_Float16)Wh[(192 + 2*j)*G4 + colB],
                            (_Float16)Wh[(193 + 2*j)*G4 + colB]};
        wl[j][colC] = f16x2{(_Float16)Wh[(192 + 2*j)*G4 + colC],
                            (_Float16)Wh[(193 + 2*j)*G4 + colC]};
        wl[j][colD] = f16x2{(_Float16)Wh[(192 + 2*j)*G4 + colD],
                            (_Float16)Wh[(193 + 2*j)*G4 + colD]};
    }
    h_f16[tid] = 0;
    for (int i = tid; i < Cc * Hh; i += 256) wout_t[i % Cc][i / Cc] = Wout[i];
    if (tid < Cc) bout_l[tid] = bout[tid];

    const unsigned short* xgB = xg + (long)b * Tt * G4;
    unsigned short xgA = xgB[colA], xgBv = xgB[colB];
    unsigned short xgC = xgB[colC], xgD = xgB[colD];
    float c_state = 0.0f;
    __syncthreads();

    const float4* hvf4 = (const float4*)h_f16;   // broadcast LDS reads
    const f16x2*  hv   = (const f16x2*)h_f16;

    // ---- time loop ----
    for (int t = 0; t < Tt; ++t) {
        // prefetch next xg (4 coalesced u16 loads; latency hides under dots)
        unsigned short nA = 0, nB = 0, nC = 0, nD = 0;
        if (t + 1 < Tt) {
            const unsigned short* xn = xgB + (long)(t + 1) * G4;
            nA = xn[colA]; nB = xn[colB]; nC = xn[colC]; nD = xn[colD];
        }

        float aA = 0.f, aB = 0.f, aC = 0.f, aD = 0.f;
        // pairs 0..51 from VGPRs
        DOTG4V(0,   0, 1, 2, 3)   DOTG4V(1,   4, 5, 6, 7)
        DOTG4V(2,   8, 9,10,11)   DOTG4V(3,  12,13,14,15)
        DOTG4V(4,  16,17,18,19)   DOTG4V(5,  20,21,22,23)
        DOTG4V(6,  24,25,26,27)   DOTG4V(7,  28,29,30,31)
        DOTG4V(8,  32,33,34,35)   DOTG4V(9,  36,37,38,39)
        DOTG4V(10, 40,41,42,43)   DOTG4V(11, 44,45,46,47)
        DOTG4V(12, 48,49,50,51)
        // pairs 52..95 from AGPRs
        DOTG4A(13, 52,53,54,55)   DOTG4A(14, 56,57,58,59)
        DOTG4A(15, 60,61,62,63)   DOTG4A(16, 64,65,66,67)
        DOTG4A(17, 68,69,70,71)   DOTG4A(18, 72,73,74,75)
        DOTG4A(19, 76,77,78,79)   DOTG4A(20, 80,81,82,83)
        DOTG4A(21, 84,85,86,87)   DOTG4A(22, 88,89,90,91)
        DOTG4A(23, 92,93,94,95)
        // pairs 96..127 from LDS (lane-consecutive b32, conflict-free)
        #pragma unroll
        for (int j = 0; j < 32; ++j) {
            f16x2 h2 = hv[96 + j];
            aA = dot2(h2, wl[j][colA], aA);
            aB = dot2(h2, wl[j][colB], aB);
            aC = dot2(h2, wl[j][colC], aC);
            aD = dot2(h2, wl[j][colD], aD);
        }

        float ig = sigm(h2f(xgA) + aA);
        float fg = sigm(h2f(xgBv) + aB);
        float gg = tanh_fast(h2f(xgC) + aC);
        float og = sigm(h2f(xgD) + aD);
        c_state = fg * c_state + ig * gg;
        float hval = og * tanh_fast(c_state);

        __syncthreads();  // B1: every thread done reading h(t-1)
        h_f16[tid] = f2h(hval);
        __syncthreads();  // B2: h(t) staged

        // fused output projection: wave w -> class w; waves 0,1 also 4,5
        const int w = tid >> 6, l = tid & 63;
        {
            float p = 0.0f;
            #pragma unroll
            for (int j = 0; j < 4; ++j)
                p += h2f(h_f16[l + 64 * j]) * wout_t[w][l + 64 * j];
            #pragma unroll
            for (int off = 32; off > 0; off >>= 1) p += __shfl_down(p, off);
            if (l == 0) out[((long)b * Tt + t) * Cc + w] = p + bout_l[w];
        }
        if (w < 2) {
            const int c2 = 4 + w;
            float p = 0.0f;
            #pragma unroll
            for (int j = 0; j < 4; ++j)
                p += h2f(h_f16[l + 64 * j]) * wout_t[c2][l + 64 * j];
            #pragma unroll
            for (int off = 32; off > 0; off >>= 1) p += __shfl_down(p, off);
            if (l == 0) out[((long)b * Tt + t) * Cc + c2] = p + bout_l[c2];
        }

        xgA = nA; xgBv = nB; xgC = nC; xgD = nD;
    }
}

// ---------------- fallback: R2 single-block kernel (no ws needed) ----------
__global__ __launch_bounds__(1024) void lstm_fused(
    const float* __restrict__ x, const float* __restrict__ Wx,
    const float* __restrict__ Wh, const float* __restrict__ bias,
    const float* __restrict__ Wout, const float* __restrict__ bout,
    float* __restrict__ out)
{
    __shared__ float h_lds[Hh];
    __shared__ float gates_lds[G4];
    __shared__ float x_lds[2][Dd];
    __shared__ float wout_t[Cc][Hh];
    __shared__ float bout_l[Cc];
    const int tid = threadIdx.x;
    const int b   = blockIdx.x;
    float wx[Dd];
    #pragma unroll
    for (int d = 0; d < Dd; ++d) wx[d] = Wx[d * G4 + tid];
    const float bj = bias[tid];
    if (tid < Hh) h_lds[tid] = 0.0f;
    for (int i = tid; i < Cc * Hh; i += 1024) wout_t[i % Cc][i / Cc] = Wout[i];
    if (tid < Cc) bout_l[tid] = bout[tid];
    const float* xB = x + (long)b * Tt * Dd;
    if (tid < Dd) x_lds[0][tid] = xB[tid];
    float c_state = 0.0f;
    __syncthreads();
    const float* WhB = Wh + tid;
    for (int t = 0; t < Tt; ++t) {
        float gg = bj;
        const float* xr = x_lds[t & 1];
        #pragma unroll
        for (int d = 0; d < Dd; ++d) gg += xr[d] * wx[d];
        #pragma unroll 8
        for (int k = 0; k < Hh; ++k) gg += h_lds[k] * WhB[k * G4];
        float a;
        if (tid < 2 * Hh)      a = 1.0f / (1.0f + expf(-gg));
        else if (tid < 3 * Hh) a = tanhf(gg);
        else                   a = 1.0f / (1.0f + expf(-gg));
        gates_lds[tid] = a;
        __syncthreads();
        if (tid < Hh) {
            float iv = gates_lds[tid], fv = gates_lds[tid + Hh];
            float gv = gates_lds[tid + 2 * Hh], ov = gates_lds[tid + 3 * Hh];
            c_state = fv * c_state + iv * gv;
            h_lds[tid] = ov * tanhf(c_state);
        } else if (tid >= 384 && tid < 448) {
            int tn = t + 1;
            if (tn < Tt) x_lds[tn & 1][tid - 384] = xB[(long)tn * Dd + (tid - 384)];
        }
        __syncthreads();
        const int w = tid >> 6, l = tid & 63;
        if (w < Cc) {
            float p = 0.0f;
            #pragma unroll
            for (int qq = 0; qq < 4; ++qq) p += h_lds[l + 64 * qq] * wout_t[w][l + 64 * qq];
            #pragma unroll
            for (int off = 32; off > 0; off >>= 1) p += __shfl_down(p, off);
            if (l == 0) out[((long)b * Tt + t) * Cc + w] = p + bout_l[w];
        }
    }
}

extern "C" void kernel_launch(void* const* d_in, const int* in_sizes, int n_in,
                              void* d_out, int out_size, void* d_ws, size_t ws_size,
                              hipStream_t stream) {
    const float* x    = (const float*)d_in[0];
    const float* Wx   = (const float*)d_in[1];
    const float* Wh   = (const float*)d_in[2];
    const float* bvec = (const float*)d_in[3];
    const float* Wout = (const float*)d_in[4];
    const float* bout = (const float*)d_in[5];
    float* outp = (float*)d_out;

    if (ws_size >= XG_BYTES) {
        unsigned short* xgws = (unsigned short*)d_ws;
        xg_gemm<<<dim3(BT / 32, 4), dim3(256), 0, stream>>>(x, Wx, bvec, xgws);
        lstm_xg<<<dim3(128), dim3(256), 0, stream>>>(xgws, Wh, Wout, bout, outp);
    } else {
        lstm_fused<<<dim3(128), dim3(1024), 0, stream>>>(x, Wx, Wh, bvec, Wout, bout, outp);
    }
}

// Round 10
// 3756.979 us; speedup vs baseline: 1.5204x; 1.5204x over previous
//
#include <hip/hip_runtime.h>
#include <math.h>

// LSTM B=128,T=1024,D=64,H=256,C=6 — R10: register-headroom + LDS-b128 + 1-barrier.
//
// R9 falsified the spill theory (AGPR pinning, FETCH=xg-only, time unchanged).
// Remaining 4.5us/step = exposed LDS at 1 wave/SIMD: 128 b32 tail reads
// (~1.2us LDS occupancy), latency re-exposed because 243/256 live VGPRs left
// no prefetch buffering, 2 barriers/step. R10:
//   * V-weights 128 (pairs 0..31), AGPR-weights 256 (pairs 32..95, max)
//     -> ~85 free VGPRs for the scheduler to deep-prefetch h reads
//   * tail (pairs 96..127) packed [8][1024] uint4 -> 32 ds_read_b128
//     (2x LDS B/cyc, 4x fewer latency events vs 128 b32)
//   * h double-buffered -> ONE barrier/step; projection after the barrier
//     overlaps the next step's dots
// Numerics identical to R8/R9 (f16 weights/h/xg, fp32 accum): absmax 3.9e-3.

#define Tt 1024
#define Dd 64
#define Hh 256
#define G4 1024
#define Cc 6
#define BT (128 * 1024)
#define XG_BYTES ((size_t)BT * G4 * 2)   // 256 MB f16

typedef _Float16 f16x2 __attribute__((ext_vector_type(2)));

__device__ __forceinline__ float dot2(f16x2 a, f16x2 b, float c) {
#if __has_builtin(__builtin_amdgcn_fdot2)
    return __builtin_amdgcn_fdot2(a, b, c, false);
#else
    return c + (float)a.x * (float)b.x + (float)a.y * (float)b.y;
#endif
}
__device__ __forceinline__ float sigm(float p) { return 1.0f / (1.0f + __expf(-p)); }
__device__ __forceinline__ float tanh_fast(float p) {
    return 1.0f - 2.0f / (__expf(2.0f * p) + 1.0f);
}
__device__ __forceinline__ unsigned short f2h(float v) {
    _Float16 h = (_Float16)v;
    return __builtin_bit_cast(unsigned short, h);
}
__device__ __forceinline__ float h2f(unsigned short u) {
    return (float)__builtin_bit_cast(_Float16, u);
}
__device__ __forceinline__ f16x2 bcf(float v) { return __builtin_bit_cast(f16x2, v); }
__device__ __forceinline__ f16x2 bcu(unsigned int v) { return __builtin_bit_cast(f16x2, v); }
__device__ __forceinline__ unsigned int packh(float a, float b) {
    return (unsigned int)f2h(a) | ((unsigned int)f2h(b) << 16);
}

// ---------------- stage 1: xg = x @ Wx + bias, f16 (verified R6-R9) --------
__global__ __launch_bounds__(256) void xg_gemm(
    const float* __restrict__ x, const float* __restrict__ Wx,
    const float* __restrict__ bias, unsigned short* __restrict__ xg)
{
    __shared__ float xs[32][65];
    __shared__ float wsl[64][256];

    const int tid = threadIdx.x;
    const long r0 = (long)blockIdx.x * 32;
    const int  c0 = blockIdx.y * 256;

    {
        const float4* src = (const float4*)(x + r0 * Dd);
        float4 v0 = src[tid], v1 = src[tid + 256];
        int e = tid * 4;
        xs[e >> 6][e & 63] = v0.x; xs[e >> 6][(e & 63) + 1] = v0.y;
        xs[e >> 6][(e & 63) + 2] = v0.z; xs[e >> 6][(e & 63) + 3] = v0.w;
        e += 1024;
        xs[e >> 6][e & 63] = v1.x; xs[e >> 6][(e & 63) + 1] = v1.y;
        xs[e >> 6][(e & 63) + 2] = v1.z; xs[e >> 6][(e & 63) + 3] = v1.w;
    }
    for (int i = tid; i < 64 * 64; i += 256) {
        int d = i >> 6, cq = i & 63;
        *(float4*)&wsl[d][cq * 4] = *(const float4*)(Wx + (long)d * G4 + c0 + cq * 4);
    }
    __syncthreads();

    const int r = tid & 31, cg = tid >> 5;
    float acc[32];
    #pragma unroll
    for (int c = 0; c < 32; ++c) acc[c] = bias[c0 + cg * 32 + c];
    for (int k = 0; k < 64; ++k) {
        float xv = xs[r][k];
        #pragma unroll
        for (int c = 0; c < 32; ++c) acc[c] += xv * wsl[k][cg * 32 + c];
    }
    unsigned int ow[16];
    #pragma unroll
    for (int c2 = 0; c2 < 16; ++c2)
        ow[c2] = packh(acc[2 * c2], acc[2 * c2 + 1]);
    uint4* dst = (uint4*)(xg + (r0 + r) * G4 + c0 + cg * 32);
    dst[0] = make_uint4(ow[0], ow[1], ow[2], ow[3]);
    dst[1] = make_uint4(ow[4], ow[5], ow[6], ow[7]);
    dst[2] = make_uint4(ow[8], ow[9], ow[10], ow[11]);
    dst[3] = make_uint4(ow[12], ow[13], ow[14], ow[15]);
}

// ---------------- stage 2: recurrence -------------------------------------
// pair index i covers k = 2i,2i+1; cols A,B,C,D = gates i,f,g,o of unit tid.

#define WLOADV4(i) \
  const f16x2 wA_##i = f16x2{(_Float16)Wh[(2*(i))*G4 + colA], (_Float16)Wh[(2*(i)+1)*G4 + colA]}; \
  const f16x2 wB_##i = f16x2{(_Float16)Wh[(2*(i))*G4 + colB], (_Float16)Wh[(2*(i)+1)*G4 + colB]}; \
  const f16x2 wC_##i = f16x2{(_Float16)Wh[(2*(i))*G4 + colC], (_Float16)Wh[(2*(i)+1)*G4 + colC]}; \
  const f16x2 wD_##i = f16x2{(_Float16)Wh[(2*(i))*G4 + colD], (_Float16)Wh[(2*(i)+1)*G4 + colD]};

#define AW1(dst, cix, i) { \
    f16x2 t_ = f16x2{(_Float16)Wh[(2*(i))*G4 + (cix)], (_Float16)Wh[(2*(i)+1)*G4 + (cix)]}; \
    asm volatile("v_accvgpr_write_b32 %0, %1" : "=a"(dst) : "v"(__builtin_bit_cast(float, t_))); }

#define WLOADA4(i) \
  float awA_##i, awB_##i, awC_##i, awD_##i; \
  AW1(awA_##i, colA, i) AW1(awB_##i, colB, i) \
  AW1(awC_##i, colC, i) AW1(awD_##i, colD, i)

#define REPV32(M) \
  M(0) M(1) M(2) M(3) M(4) M(5) M(6) M(7) \
  M(8) M(9) M(10) M(11) M(12) M(13) M(14) M(15) \
  M(16) M(17) M(18) M(19) M(20) M(21) M(22) M(23) \
  M(24) M(25) M(26) M(27) M(28) M(29) M(30) M(31)

#define REPA64(M) \
  M(32) M(33) M(34) M(35) M(36) M(37) M(38) M(39) \
  M(40) M(41) M(42) M(43) M(44) M(45) M(46) M(47) \
  M(48) M(49) M(50) M(51) M(52) M(53) M(54) M(55) \
  M(56) M(57) M(58) M(59) M(60) M(61) M(62) M(63) \
  M(64) M(65) M(66) M(67) M(68) M(69) M(70) M(71) \
  M(72) M(73) M(74) M(75) M(76) M(77) M(78) M(79) \
  M(80) M(81) M(82) M(83) M(84) M(85) M(86) M(87) \
  M(88) M(89) M(90) M(91) M(92) M(93) M(94) M(95)

#define DOTPV(i, hh) { f16x2 h_ = (hh); \
    aA = dot2(h_, wA_##i, aA); aB = dot2(h_, wB_##i, aB); \
    aC = dot2(h_, wC_##i, aC); aD = dot2(h_, wD_##i, aD); }

#define DOTPA(i, hh) { f16x2 h_ = (hh); float tA_, tB_, tC_, tD_; \
    asm volatile("v_accvgpr_read_b32 %0, %1" : "=v"(tA_) : "a"(awA_##i)); \
    asm volatile("v_accvgpr_read_b32 %0, %1" : "=v"(tB_) : "a"(awB_##i)); \
    asm volatile("v_accvgpr_read_b32 %0, %1" : "=v"(tC_) : "a"(awC_##i)); \
    asm volatile("v_accvgpr_read_b32 %0, %1" : "=v"(tD_) : "a"(awD_##i)); \
    aA = dot2(h_, bcf(tA_), aA); aB = dot2(h_, bcf(tB_), aB); \
    aC = dot2(h_, bcf(tC_), aC); aD = dot2(h_, bcf(tD_), aD); }

#define DOTG4V(g, i0,i1,i2,i3) { float4 hC_ = hvf4[g]; \
    DOTPV(i0, bcf(hC_.x)) DOTPV(i1, bcf(hC_.y)) \
    DOTPV(i2, bcf(hC_.z)) DOTPV(i3, bcf(hC_.w)) }

#define DOTG4A(g, i0,i1,i2,i3) { float4 hC_ = hvf4[g]; \
    DOTPA(i0, bcf(hC_.x)) DOTPA(i1, bcf(hC_.y)) \
    DOTPA(i2, bcf(hC_.z)) DOTPA(i3, bcf(hC_.w)) }

__global__ __launch_bounds__(256, 1) void lstm_xg(
    const unsigned short* __restrict__ xg,  // [B,T,1024] f16, bias folded
    const float* __restrict__ Wh,           // [H,4H]
    const float* __restrict__ Wout,         // [H,C]
    const float* __restrict__ bout,         // [C]
    float* __restrict__ out)                // [B,T,C]
{
    __shared__ alignas(16) unsigned short h_buf[2][Hh];  // double-buffered h
    __shared__ uint4 wl4[8][G4];       // tail pairs 96..127: 4 pairs/read, 128 KB
    __shared__ float wout_t[Cc][Hh];
    __shared__ float bout_l[8];

    const int tid  = threadIdx.x;
    const int b    = blockIdx.x;
    const int colA = tid;          // gate i of unit tid
    const int colB = tid + 256;    // f
    const int colC = tid + 512;    // g
    const int colD = tid + 768;    // o

    // ---- prologue: 128 V-regs + 256 AGPRs + packed LDS tail ----
    REPV32(WLOADV4)
    REPA64(WLOADA4)

    #pragma unroll
    for (int jq = 0; jq < 8; ++jq) {   // pairs 96+4jq..96+4jq+3 = k rows 192+8jq..+7
        const int kb = 192 + 8 * jq;
        wl4[jq][colA] = make_uint4(
            packh(Wh[(kb+0)*G4 + colA], Wh[(kb+1)*G4 + colA]),
            packh(Wh[(kb+2)*G4 + colA], Wh[(kb+3)*G4 + colA]),
            packh(Wh[(kb+4)*G4 + colA], Wh[(kb+5)*G4 + colA]),
            packh(Wh[(kb+6)*G4 + colA], Wh[(kb+7)*G4 + colA]));
        wl4[jq][colB] = make_uint4(
            packh(Wh[(kb+0)*G4 + colB], Wh[(kb+1)*G4 + colB]),
            packh(Wh[(kb+2)*G4 + colB], Wh[(kb+3)*G4 + colB]),
            packh(Wh[(kb+4)*G4 + colB], Wh[(kb+5)*G4 + colB]),
            packh(Wh[(kb+6)*G4 + colB], Wh[(kb+7)*G4 + colB]));
        wl4[jq][colC] = make_uint4(
            packh(Wh[(kb+0)*G4 + colC], Wh[(kb+1)*G4 + colC]),
            packh(Wh[(kb+2)*G4 + colC], Wh[(kb+3)*G4 + colC]),
            packh(Wh[(kb+4)*G4 + colC], Wh[(kb+5)*G4 + colC]),
            packh(Wh[(kb+6)*G4 + colC], Wh[(kb+7)*G4 + colC]));
        wl4[jq][colD] = make_uint4(
            packh(Wh[(kb+0)*G4 + colD], Wh[(kb+1)*G4 + colD]),
            packh(Wh[(kb+2)*G4 + colD], Wh[(kb+3)*G4 + colD]),
            packh(Wh[(kb+4)*G4 + colD], Wh[(kb+5)*G4 + colD]),
            packh(Wh[(kb+6)*G4 + colD], Wh[(kb+7)*G4 + colD]));
    }
    h_buf[0][tid] = 0;
    for (int i = tid; i < Cc * Hh; i += 256) wout_t[i % Cc][i / Cc] = Wout[i];
    if (tid < Cc) bout_l[tid] = bout[tid];

    const unsigned short* xgB = xg + (long)b * Tt * G4;
    unsigned short xgA = xgB[colA], xgBv = xgB[colB];
    unsigned short xgC = xgB[colC], xgD = xgB[colD];
    float c_state = 0.0f;
    int par = 0;
    __syncthreads();

    // ---- time loop (ONE barrier per step) ----
    for (int t = 0; t < Tt; ++t) {
        // prefetch next xg (hidden under dots)
        unsigned short nA = 0, nB = 0, nC = 0, nD = 0;
        if (t + 1 < Tt) {
            const unsigned short* xn = xgB + (long)(t + 1) * G4;
            nA = xn[colA]; nB = xn[colB]; nC = xn[colC]; nD = xn[colD];
        }

        const float4* hvf4 = (const float4*)h_buf[par];  // h(t-1)
        float aA = 0.f, aB = 0.f, aC = 0.f, aD = 0.f;
        // pairs 0..31 from VGPRs
        DOTG4V(0,   0, 1, 2, 3)   DOTG4V(1,   4, 5, 6, 7)
        DOTG4V(2,   8, 9,10,11)   DOTG4V(3,  12,13,14,15)
        DOTG4V(4,  16,17,18,19)   DOTG4V(5,  20,21,22,23)
        DOTG4V(6,  24,25,26,27)   DOTG4V(7,  28,29,30,31)
        // pairs 32..95 from AGPRs
        DOTG4A(8,  32,33,34,35)   DOTG4A(9,  36,37,38,39)
        DOTG4A(10, 40,41,42,43)   DOTG4A(11, 44,45,46,47)
        DOTG4A(12, 48,49,50,51)   DOTG4A(13, 52,53,54,55)
        DOTG4A(14, 56,57,58,59)   DOTG4A(15, 60,61,62,63)
        DOTG4A(16, 64,65,66,67)   DOTG4A(17, 68,69,70,71)
        DOTG4A(18, 72,73,74,75)   DOTG4A(19, 76,77,78,79)
        DOTG4A(20, 80,81,82,83)   DOTG4A(21, 84,85,86,87)
        DOTG4A(22, 88,89,90,91)   DOTG4A(23, 92,93,94,95)
        // pairs 96..127 from LDS: 4 b128 h-free reads per col-group
        #pragma unroll
        for (int jq = 0; jq < 8; ++jq) {
            float4 hc = hvf4[24 + jq];             // 4 h-pairs (broadcast)
            uint4 wA = wl4[jq][colA];
            uint4 wB = wl4[jq][colB];
            uint4 wC = wl4[jq][colC];
            uint4 wD = wl4[jq][colD];
            f16x2 h0 = bcf(hc.x), h1 = bcf(hc.y), h2 = bcf(hc.z), h3 = bcf(hc.w);
            aA = dot2(h0, bcu(wA.x), aA); aA = dot2(h1, bcu(wA.y), aA);
            aA = dot2(h2, bcu(wA.z), aA); aA = dot2(h3, bcu(wA.w), aA);
            aB = dot2(h0, bcu(wB.x), aB); aB = dot2(h1, bcu(wB.y), aB);
            aB = dot2(h2, bcu(wB.z), aB); aB = dot2(h3, bcu(wB.w), aB);
            aC = dot2(h0, bcu(wC.x), aC); aC = dot2(h1, bcu(wC.y), aC);
            aC = dot2(h2, bcu(wC.z), aC); aC = dot2(h3, bcu(wC.w), aC);
            aD = dot2(h0, bcu(wD.x), aD); aD = dot2(h1, bcu(wD.y), aD);
            aD = dot2(h2, bcu(wD.z), aD); aD = dot2(h3, bcu(wD.w), aD);
        }

        float ig = sigm(h2f(xgA) + aA);
        float fg = sigm(h2f(xgBv) + aB);
        float gg = tanh_fast(h2f(xgC) + aC);
        float og = sigm(h2f(xgD) + aD);
        c_state = fg * c_state + ig * gg;
        float hval = og * tanh_fast(c_state);

        h_buf[par ^ 1][tid] = f2h(hval);   // write h(t) to the other buffer
        __syncthreads();                    // single barrier: h(t) visible,
                                            // h(t-1) reads all done
        // fused output projection on h(t); overlaps next step's dots
        const unsigned short* hn = h_buf[par ^ 1];
        const int w = tid >> 6, l = tid & 63;
        {
            float p = 0.0f;
            #pragma unroll
            for (int j = 0; j < 4; ++j)
                p += h2f(hn[l + 64 * j]) * wout_t[w][l + 64 * j];
            #pragma unroll
            for (int off = 32; off > 0; off >>= 1) p += __shfl_down(p, off);
            if (l == 0) out[((long)b * Tt + t) * Cc + w] = p + bout_l[w];
        }
        if (w < 2) {
            const int c2 = 4 + w;
            float p = 0.0f;
            #pragma unroll
            for (int j = 0; j < 4; ++j)
                p += h2f(hn[l + 64 * j]) * wout_t[c2][l + 64 * j];
            #pragma unroll
            for (int off = 32; off > 0; off >>= 1) p += __shfl_down(p, off);
            if (l == 0) out[((long)b * Tt + t) * Cc + c2] = p + bout_l[c2];
        }

        xgA = nA; xgBv = nB; xgC = nC; xgD = nD;
        par ^= 1;
    }
}

// ---------------- fallback: R2 single-block kernel (no ws needed) ----------
__global__ __launch_bounds__(1024) void lstm_fused(
    const float* __restrict__ x, const float* __restrict__ Wx,
    const float* __restrict__ Wh, const float* __restrict__ bias,
    const float* __restrict__ Wout, const float* __restrict__ bout,
    float* __restrict__ out)
{
    __shared__ float h_lds[Hh];
    __shared__ float gates_lds[G4];
    __shared__ float x_lds[2][Dd];
    __shared__ float wout_t[Cc][Hh];
    __shared__ float bout_l[Cc];
    const int tid = threadIdx.x;
    const int b   = blockIdx.x;
    float wx[Dd];
    #pragma unroll
    for (int d = 0; d < Dd; ++d) wx[d] = Wx[d * G4 + tid];
    const float bj = bias[tid];
    if (tid < Hh) h_lds[tid] = 0.0f;
    for (int i = tid; i < Cc * Hh; i += 1024) wout_t[i % Cc][i / Cc] = Wout[i];
    if (tid < Cc) bout_l[tid] = bout[tid];
    const float* xB = x + (long)b * Tt * Dd;
    if (tid < Dd) x_lds[0][tid] = xB[tid];
    float c_state = 0.0f;
    __syncthreads();
    const float* WhB = Wh + tid;
    for (int t = 0; t < Tt; ++t) {
        float gg = bj;
        const float* xr = x_lds[t & 1];
        #pragma unroll
        for (int d = 0; d < Dd; ++d) gg += xr[d] * wx[d];
        #pragma unroll 8
        for (int k = 0; k < Hh; ++k) gg += h_lds[k] * WhB[k * G4];
        float a;
        if (tid < 2 * Hh)      a = 1.0f / (1.0f + expf(-gg));
        else if (tid < 3 * Hh) a = tanhf(gg);
        else                   a = 1.0f / (1.0f + expf(-gg));
        gates_lds[tid] = a;
        __syncthreads();
        if (tid < Hh) {
            float iv = gates_lds[tid], fv = gates_lds[tid + Hh];
            float gv = gates_lds[tid + 2 * Hh], ov = gates_lds[tid + 3 * Hh];
            c_state = fv * c_state + iv * gv;
            h_lds[tid] = ov * tanhf(c_state);
        } else if (tid >= 384 && tid < 448) {
            int tn = t + 1;
            if (tn < Tt) x_lds[tn & 1][tid - 384] = xB[(long)tn * Dd + (tid - 384)];
        }
        __syncthreads();
        const int w = tid >> 6, l = tid & 63;
        if (w < Cc) {
            float p = 0.0f;
            #pragma unroll
            for (int qq = 0; qq < 4; ++qq) p += h_lds[l + 64 * qq] * wout_t[w][l + 64 * qq];
            #pragma unroll
            for (int off = 32; off > 0; off >>= 1) p += __shfl_down(p, off);
            if (l == 0) out[((long)b * Tt + t) * Cc + w] = p + bout_l[w];
        }
    }
}

extern "C" void kernel_launch(void* const* d_in, const int* in_sizes, int n_in,
                              void* d_out, int out_size, void* d_ws, size_t ws_size,
                              hipStream_t stream) {
    const float* x    = (const float*)d_in[0];
    const float* Wx   = (const float*)d_in[1];
    const float* Wh   = (const float*)d_in[2];
    const float* bvec = (const float*)d_in[3];
    const float* Wout = (const float*)d_in[4];
    const float* bout = (const float*)d_in[5];
    float* outp = (float*)d_out;

    if (ws_size >= XG_BYTES) {
        unsigned short* xgws = (unsigned short*)d_ws;
        xg_gemm<<<dim3(BT / 32, 4), dim3(256), 0, stream>>>(x, Wx, bvec, xgws);
        lstm_xg<<<dim3(128), dim3(256), 0, stream>>>(xgws, Wh, Wout, bout, outp);
    } else {
        lstm_fused<<<dim3(128), dim3(1024), 0, stream>>>(x, Wx, Wh, bvec, Wout, bout, outp);
    }
}